// Round 11
// baseline (633.376 us; speedup 1.0000x reference)
//
#include <hip/hip_runtime.h>
#include <stdint.h>

typedef unsigned int u32;
using i32x4 = __attribute__((ext_vector_type(4))) int;

// async global->LDS, 16B per lane, dest = wave-uniform base + lane*16
#define GLD_LDS16(SRC, DST)                                      \
  __builtin_amdgcn_global_load_lds(                              \
      (const __attribute__((address_space(1))) void*)(SRC),      \
      (__attribute__((address_space(3))) void*)(DST), 16, 0, 0)

#define SCHED0() __builtin_amdgcn_sched_barrier(0)
#define BAR()    __builtin_amdgcn_s_barrier()
#define PRIO(x)  __builtin_amdgcn_s_setprio(x)

// ---------- pass 1: per-row symmetric int8 quant (x rows, then w rows) ----------
__global__ __launch_bounds__(256)
void quant_rows(const float* __restrict__ x, const float* __restrict__ w,
                signed char* __restrict__ xq, signed char* __restrict__ wq,
                float* __restrict__ sx, float* __restrict__ sw,
                int Mrows, int totRows, int K) {
  __shared__ float red[4];
  for (int row = blockIdx.x; row < totRows; row += gridDim.x) {
    const bool isx = row < Mrows;
    const float* src = isx ? x + (size_t)row * K : w + (size_t)(row - Mrows) * K;
    const float4* s4 = reinterpret_cast<const float4*>(src) + threadIdx.x * 4;
    float4 v[4];
#pragma unroll
    for (int g = 0; g < 4; ++g) v[g] = s4[g];
    float am = 0.f;
#pragma unroll
    for (int g = 0; g < 4; ++g)
      am = fmaxf(am, fmaxf(fmaxf(fabsf(v[g].x), fabsf(v[g].y)),
                           fmaxf(fabsf(v[g].z), fabsf(v[g].w))));
#pragma unroll
    for (int m = 1; m <= 32; m <<= 1) am = fmaxf(am, __shfl_xor(am, m));
    if ((threadIdx.x & 63) == 0) red[threadIdx.x >> 6] = am;
    __syncthreads();
    am = fmaxf(fmaxf(red[0], red[1]), fmaxf(red[2], red[3]));
    const float s   = am > 0.f ? am * (1.f / 127.f) : 1.f;
    const float inv = am > 0.f ? 127.f / am : 0.f;
    u32 pk[4];
#pragma unroll
    for (int g = 0; g < 4; ++g) {
      const float* vp = reinterpret_cast<const float*>(&v[g]);
      u32 p = 0;
#pragma unroll
      for (int e = 0; e < 4; ++e) {
        int q = (int)rintf(vp[e] * inv);
        q = q < -127 ? -127 : (q > 127 ? 127 : q);
        p |= ((u32)(q & 0xff)) << (8 * e);
      }
      pk[g] = p;
    }
    signed char* dst = (isx ? xq + (size_t)row * K : wq + (size_t)(row - Mrows) * K)
                       + threadIdx.x * 16;
    *reinterpret_cast<uint4*>(dst) = make_uint4(pk[0], pk[1], pk[2], pk[3]);
    if (threadIdx.x == 0) { if (isx) sx[row] = s; else sw[row - Mrows] = s; }
    __syncthreads();
  }
}

// ---------- pass 2: int8 GEMM BK=128, split aged vmcnt gates ----------
// Structure/addressing/swizzle identical to verified round-9 (absmax 0.1015625,
// 0 bank conflicts). Changes vs r9: (1) STAGE at region START (right after BAR),
// (2) TWO vmcnt(8) gates draining only tile-old loads:
//   Region 1: BAR | stage B(t+2)->cur | rd afB(1,0) | C1 | rd afA(0,1) | C2 |
//             rd afB(1,1) | vmcnt(8)  <- drains B(t+1), staged 2 regions ago
//   Region 2: BAR | stage A(t+2)->cur | rd bP<-B(t+1,0) | C3 | vmcnt(8)
//             <- drains A(t+1), staged ~2 regions ago | rd afA<-A(t+1,0,0) |
//             C4 | rd bQ<-B(t+1,1)
// Ledger (per wave, order of issue): steady entry = {B(t+1):4, A(t+1):4}.
//   R1: +B(t+2) -> 12; vmcnt(8) drains oldest 4 = B(t+1).
//   R2: +A(t+2) -> 12; vmcnt(8) drains oldest 4 = A(t+1). Exit = 8. OK.
// bP/bQ reads (region 2) come after gate 1 (B(t+1) landed); afA(t+1) read comes
// after gate 2. Prologue stages B(t1) BEFORE A(t1) to match steady-state ordering.
__global__ __launch_bounds__(512, 2)
void gemm_i8_gate(const signed char* __restrict__ A,   // [M][K] i8
                  const signed char* __restrict__ B,   // [N][K] i8
                  const float* __restrict__ sx,        // [M]
                  const float* __restrict__ sw,        // [N]
                  const float* __restrict__ wscale_p,  // [1]
                  const float* __restrict__ bias,      // [N]
                  float* __restrict__ C,               // [M][N] fp32
                  int Nn, int Kk, int NT) {
  __shared__ signed char lds[2][2][256 * 128];

  const int tid  = threadIdx.x;
  const int lane = tid & 63;
  const int wave = tid >> 6;       // 0..7
  const int wr = wave >> 2;        // 0..1 (M)
  const int wc = wave & 3;         // 0..3 (N)

  // T1: XCD-aware swizzle (gridDim.x == 2048, divisible by 8)
  const int bid = blockIdx.x;
  const int cpx = gridDim.x >> 3;
  const int wg  = (bid & 7) * cpx + (bid >> 3);
  const int mt = wg / NT, nt = wg % NT;
  const int m0 = mt * 256, n0 = nt * 256;

  // staging: per gload instr, 64 lanes = 8 rows x 128B; lane l -> row l>>3, slot l&7
  const int srow = lane >> 3;
  const int ss   = (lane & 7) ^ (srow & 7);   // inverse-swizzled source k-slot
  const int r16  = lane & 15;
  const int kq   = lane >> 4;

  const signed char* ga = A + ((size_t)m0 + wave * 32 + srow) * Kk + ss * 16;
  const signed char* gb = B + ((size_t)n0 + wave * 32 + srow) * Kk + ss * 16;

  // fragment byte offsets: row*128 + ((kq ^ (row&7))<<4); ks=1 flips byte bit 6
  const int aoff = (wr * 128 + r16) * 128 + ((kq ^ (r16 & 7)) << 4);
  const int boff = (wc * 64  + r16) * 128 + ((kq ^ (r16 & 7)) << 4);

  i32x4 acc[8][4];
#pragma unroll
  for (int i = 0; i < 8; ++i)
#pragma unroll
    for (int j = 0; j < 4; ++j)
      acc[i][j] = (i32x4){0, 0, 0, 0};

  i32x4 afA[4], afB[4];   // A frag sets (roles rotate across clusters)
  i32x4 bP[4], bQ[4];     // B frags ks0 / ks1

#define STAGE128(bfi_, op_, kt_) do {                                           \
    const signed char* _g = ((op_) ? gb : ga) + (size_t)(kt_) * 128;            \
    signed char* _d = &lds[bfi_][op_][wave * 32 * 128];                         \
    GLD_LDS16(_g,                    _d);                                       \
    GLD_LDS16(_g + (size_t)8  * Kk,  _d + 1024);                                \
    GLD_LDS16(_g + (size_t)16 * Kk,  _d + 2048);                                \
    GLD_LDS16(_g + (size_t)24 * Kk,  _d + 3072);                                \
  } while (0)

#define LDFA(AF_, la_, mh_, ks_) do {                                           \
    _Pragma("unroll") for (int _i = 0; _i < 4; ++_i)                            \
      AF_[_i] = *reinterpret_cast<const i32x4*>(                                \
          (la_) + ((aoff + ((mh_) * 4 + _i) * 2048) ^ ((ks_) << 6)));           \
  } while (0)

#define LDFB(BF_, lb_, ks_) do {                                                \
    _Pragma("unroll") for (int _n = 0; _n < 4; ++_n)                            \
      BF_[_n] = *reinterpret_cast<const i32x4*>(                                \
          (lb_) + ((boff + _n * 2048) ^ ((ks_) << 6)));                         \
  } while (0)

#define MFMAC(mh_, AF_, BF_)                                                    \
  _Pragma("unroll") for (int i = 0; i < 4; ++i)                                 \
  _Pragma("unroll") for (int n = 0; n < 4; ++n)                                 \
    acc[(mh_) * 4 + i][n] = __builtin_amdgcn_mfma_i32_16x16x64_i8(              \
        AF_[i], BF_[n], acc[(mh_) * 4 + i][n], 0, 0, 0)

  const int KT = Kk >> 7;   // K/128 = 32

  // ---- prologue: t0 (A,B) -> buf0, then B(t1), A(t1) -> buf1 (order matters:
  // steady state expects B(t+1) older than A(t+1)); drain t0; pre-read t0 frags ----
  STAGE128(0, 0, 0); STAGE128(0, 1, 0);
  STAGE128(1, 1, 1);            // B(t1) first
  STAGE128(1, 0, 1);            // A(t1) second
  asm volatile("s_waitcnt vmcnt(8)" ::: "memory");
  SCHED0(); BAR(); SCHED0();
  LDFA(afA, (const signed char*)&lds[0][0][0], 0, 0);
  LDFB(bP,  (const signed char*)&lds[0][1][0], 0);
  LDFB(bQ,  (const signed char*)&lds[0][1][0], 1);

#define TILE128(t_, CUR_) do {                                                  \
    const signed char* laC = &lds[CUR_][0][0];                                  \
    const signed char* laN = &lds[(CUR_) ^ 1][0][0];                            \
    const signed char* lbN = &lds[(CUR_) ^ 1][1][0];                            \
    const int kt2 = ((t_) + 2 < KT) ? (t_) + 2 : KT - 1;                        \
    /* ---- region 1 ---- */                                                    \
    SCHED0(); BAR(); SCHED0();                                                  \
    STAGE128(CUR_, 1, kt2);                   /* B(t+2)->cur, issue FIRST */    \
    LDFA(afB, laC, 1, 0);                                                       \
    PRIO(1); MFMAC(0, afA, bP); PRIO(0);      /* C1: mh0,ks0 */                 \
    LDFA(afA, laC, 0, 1);                                                       \
    PRIO(1); MFMAC(1, afB, bP); PRIO(0);      /* C2: mh1,ks0 */                 \
    LDFA(afB, laC, 1, 1);                                                       \
    SCHED0();                                                                   \
    asm volatile("s_waitcnt vmcnt(8)" ::: "memory");  /* drains B(t+1) */       \
    /* ---- region 2 ---- */                                                    \
    SCHED0(); BAR(); SCHED0();                                                  \
    STAGE128(CUR_, 0, kt2);                   /* A(t+2)->cur, issue FIRST */    \
    LDFB(bP, lbN, 0);                         /* B(t+1) ks0: landed (gate 1) */ \
    PRIO(1); MFMAC(0, afA, bQ); PRIO(0);      /* C3: mh0,ks1 */                 \
    SCHED0();                                                                   \
    asm volatile("s_waitcnt vmcnt(8)" ::: "memory");  /* drains A(t+1) */       \
    SCHED0();                                                                   \
    LDFA(afA, laN, 0, 0);                     /* A(t+1): landed (gate 2) */     \
    PRIO(1); MFMAC(1, afB, bQ); PRIO(0);      /* C4: mh1,ks1 */                 \
    LDFB(bQ, lbN, 1);                         /* bQ dead only after C4 */       \
  } while (0)

  for (int t = 0; t < KT; t += 2) {
    TILE128(t,     0);
    TILE128(t + 1, 1);
  }

  // ---- epilogue: out = acc * sx[row] * (sw[col]*wscale) + bias ----
  const float wsc = wscale_p[0];
  float cw[4], bv[4];
#pragma unroll
  for (int ni = 0; ni < 4; ++ni) {
    const int col = n0 + wc * 64 + ni * 16 + r16;
    cw[ni] = sw[col] * wsc;
    bv[ni] = bias[col];
  }
#pragma unroll
  for (int mi = 0; mi < 8; ++mi) {
#pragma unroll
    for (int r = 0; r < 4; ++r) {
      // C/D layout (16x16 shapes, dtype-independent): col = lane&15, row = (lane>>4)*4 + reg
      const int row = m0 + wr * 128 + mi * 16 + kq * 4 + r;
      const float sxr = sx[row];
      float* cp = C + (size_t)row * Nn + (n0 + wc * 64 + r16);
#pragma unroll
      for (int ni = 0; ni < 4; ++ni)
        cp[ni * 16] = (float)acc[mi][ni][r] * (sxr * cw[ni]) + bv[ni];
    }
  }
#undef STAGE128
#undef LDFA
#undef LDFB
#undef MFMAC
#undef TILE128
}

extern "C" void kernel_launch(void* const* d_in, const int* in_sizes, int n_in,
                              void* d_out, int out_size, void* d_ws, size_t ws_size,
                              hipStream_t stream) {
  (void)n_in; (void)out_size; (void)ws_size;
  const float* x  = (const float*)d_in[0];   // [M][K] fp32
  const float* w  = (const float*)d_in[1];   // [N][K] fp32 (fp8-representable values)
  const float* sc = (const float*)d_in[2];   // [1]
  const float* bs = (const float*)d_in[3];   // [N]
  float* out = (float*)d_out;                // [M][N] fp32

  const int N = in_sizes[3];        // 16384
  const int K = in_sizes[1] / N;    // 4096
  const int M = in_sizes[0] / K;    // 8192

  signed char* xq = (signed char*)d_ws;            // [M][K] i8  (32 MB)
  signed char* wq = xq + (size_t)M * K;            // [N][K] i8  (64 MB)
  float* sxp = (float*)(wq + (size_t)N * K);       // [M]
  float* swp = sxp + M;                            // [N]

  quant_rows<<<M + N, 256, 0, stream>>>(x, w, xq, wq, sxp, swp, M, M + N, K);

  const int NT = N / 256;
  const int nwg = (M / 256) * NT;                  // 2048, % 8 == 0
  gemm_i8_gate<<<nwg, 512, 0, stream>>>(xq, wq, sxp, swp, sc, bs, out, N, K, NT);
}